// Round 5
// baseline (315.643 us; speedup 1.0000x reference)
//
#include <hip/hip_runtime.h>

// Round 8: R7 structure, spill fix.
//   R7's __launch_bounds__(512,2) capped VGPR at 128; persistent state is ~152
//   regs -> spill-to-scratch (FETCH +130MB, WRITE +95MB, the whole R7 regression).
//   Fix: __launch_bounds__(512) alone -> hard cap 256 (8 waves = 2/SIMD, which
//   LDS pins anyway). Everything else unchanged:
//   - LDS 163840 B exactly: xs[4][16][256] 64K + W2 frags 32K + 8 wave-regions 64K
//   - x staged via global_load_lds width16 (no staging VGPRs, async under MLP)
//   - W1/W3 frags LDS-bounced once per block; b1 folded as k=48 MFMA column
//   - MLP: feats preload->regs, H overlays wave region, bounce transpose, 256B stores

#define NPX (1u << 20)

using bf16x8 = __attribute__((ext_vector_type(8))) __bf16;
using f32x4  = __attribute__((ext_vector_type(4))) float;

__device__ __forceinline__ unsigned f2bf(float f) {
    unsigned u = __float_as_uint(f);
    u += 0x7fffu + ((u >> 16) & 1u);   // RNE; inputs finite
    return u >> 16;
}

// ---- ws layout (ushort offsets): weight frags only ----
#define WS1_OFF 0        // [mt=8][kb=2][lane=64][8]  A-frags of W1^T (K-pad 48->64; k=48 = b1)
#define WS2_OFF 8192     // [mt=8][kb=4][lane=64][8]  A-frags of W2^T
#define WS3_OFF 24576    // [kb=4][lane=64][8]        A-frags of W3^T

__global__ __launch_bounds__(256)
void prep_weights(const float* __restrict__ w1, const float* __restrict__ b1,
                  const float* __restrict__ w2, const float* __restrict__ w3,
                  unsigned short* __restrict__ ws) {
    const int gid = blockIdx.x * 256 + threadIdx.x;   // 13 blocks x 256 = 3328 slots
    if (gid < 1024) {   // ws1 (feature order k = 3*c + t; w1 row = t*16 + c; k=48 -> b1)
        const int s = gid;
        const int mt = s >> 7, kb = (s >> 6) & 1, lane = s & 63;
        const int q = lane >> 4, ln = lane & 15;
#pragma unroll
        for (int j = 0; j < 8; ++j) {
            const int k = kb * 32 + q * 8 + j;
            float val = 0.f;
            if (k < 48) { const int c = k / 3, t = k - 3 * c; val = w1[(t * 16 + c) * 128 + mt * 16 + ln]; }
            else if (k == 48) val = b1[mt * 16 + ln];   // bias column (B side supplies 1.0)
            ws[WS1_OFF + s * 8 + j] = (unsigned short)f2bf(val);
        }
    } else if (gid < 3072) {   // ws2
        const int s2 = gid - 1024;
        const int mt = s2 >> 8, kb = (s2 >> 6) & 3, lane = s2 & 63;
        const int q = lane >> 4, ln = lane & 15;
#pragma unroll
        for (int j = 0; j < 8; ++j) {
            const int k = kb * 32 + q * 8 + j;
            ws[WS2_OFF + s2 * 8 + j] = (unsigned short)f2bf(w2[k * 128 + mt * 16 + ln]);
        }
    } else if (gid < 3328) {   // ws3
        const int s3 = gid - 3072;
        const int kb = s3 >> 6, lane = s3 & 63;
        const int q = lane >> 4, ln = lane & 15;
#pragma unroll
        for (int j = 0; j < 8; ++j) {
            const int k = kb * 32 + q * 8 + j;
            ws[WS3_OFF + s3 * 8 + j] = (unsigned short)f2bf(w3[k * 16 + ln]);
        }
    }
}

// ===================== fused kernel =====================
// 512 blocks = 16 batches x 32 strips of 8 rows; 512 threads = 8 waves.
// Iteration i covers rows r0=h0+2i, r0+1: waves 0-3 -> row r0 (cols 64w..),
// waves 4-7 -> row r0+1. Wave w's region holds feats/H for its own 64-px tile.

// LDS layout (bytes), total 163840 (full pool, 1 block/CU, 8 waves = 2/SIMD):
#define SM_XS    0       // float xs[4][16][256] rolling row window   = 65536
#define SM_W2    65536   // W2 A-frags (also W1/W3 bounce at init)    = 32768
#define SM_WR    98304   // 8 wave regions x 8192                     = 65536
#define SM_TOTAL 163840

#define H_SWZ(j, ln) ((((j) ^ ((ln) & 7)) << 4))

#define GLDS16(gp, lp) __builtin_amdgcn_global_load_lds(                     \
    (const __attribute__((address_space(1))) void*)(gp),                     \
    (__attribute__((address_space(3))) void*)(lp), 16, 0, 0)

// stage one (ch,row) pair -> xs[row&3][ch][*]; row/ch wave-uniform.
// dest = wave-uniform base + lane*16 (global_load_lds semantics); OOB rows zero-fill.
#define STAGE_UNIT(chv, rowv) do {                                           \
        const int _sl = (rowv) & 3;                                          \
        char* _ld = smem + SM_XS + (size_t)(((_sl) * 16 + (chv)) * 256) * 4; \
        if ((unsigned)(rowv) < 256u) {                                       \
            const float* _gs = xb + ((size_t)(chv) << 16)                    \
                             + (size_t)(unsigned)(rowv) * 256 + lane * 4;    \
            GLDS16(_gs, _ld);                                                \
        } else {                                                             \
            *(float4*)(_ld + lane * 16) = make_float4(0.f, 0.f, 0.f, 0.f);   \
        } } while (0)

extern "C" __global__ __launch_bounds__(512)
void fused_kernel(const float* __restrict__ x, const float* __restrict__ fmask,
                  const unsigned short* __restrict__ wf,
                  const float* __restrict__ b2, const float* __restrict__ b3,
                  float* __restrict__ out) {
    extern __shared__ char smem[];
    float (*xs)[16][256] = (float (*)[16][256])(smem + SM_XS);
    char* W2L = smem + SM_W2;

    const int t = threadIdx.x;
    const int wv = t >> 6, lane = t & 63;
    const int q = lane >> 4, ln = lane & 15;
    const int rhalf = t >> 8;              // 0: waves 0-3, 1: waves 4-7
    const int col = t & 255;
    char* region = smem + SM_WR + wv * 8192;   // feats phase / H + bounce in MLP phase
    char* H = region;                          // 4096 B
    float* bounce = (float*)(region + 4096);   // [16 ch][64 px] = 4096 B

    const int bb = blockIdx.x >> 5;
    const int h0 = (blockIdx.x & 31) << 3;
    const float* xb = x + ((size_t)bb << 20);

    // ---- stage W1/W3 frag tables through LDS (ws read once per block) ----
    {
        const uint4* s1 = (const uint4*)(wf + WS1_OFF);   // 1024 uint4 = 16 KB
        uint4* dW = (uint4*)W2L;
        dW[t]       = s1[t];
        dW[t + 512] = s1[t + 512];
        if (t < 256) dW[1024 + t] = ((const uint4*)(wf + WS3_OFF))[t];   // 4 KB
    }
    __syncthreads();
    bf16x8 W1f[8][2], W3f[4];
#pragma unroll
    for (int mt = 0; mt < 8; ++mt) {
        W1f[mt][0] = *(const bf16x8*)(W2L + ((mt * 2 + 0) * 64 + lane) * 16);
        W1f[mt][1] = *(const bf16x8*)(W2L + ((mt * 2 + 1) * 64 + lane) * 16);
    }
#pragma unroll
    for (int kb = 0; kb < 4; ++kb)
        W3f[kb] = *(const bf16x8*)(W2L + 16384 + (kb * 64 + lane) * 16);
    __syncthreads();
    {   // now stage W2 frags (overwrites the bounce area)
        const uint4* s2 = (const uint4*)(wf + WS2_OFF);   // 2048 uint4 = 32 KB
        uint4* dW = (uint4*)W2L;
#pragma unroll
        for (int i2 = 0; i2 < 4; ++i2) dW[t + i2 * 512] = s2[t + i2 * 512];
    }
    // ---- biases -> VGPRs (loop-invariant) ----
    f32x4 bz2[8];
#pragma unroll
    for (int mt = 0; mt < 8; ++mt) bz2[mt] = *(const f32x4*)(b2 + mt * 16 + q * 4);
    const f32x4 bz3 = *(const f32x4*)(b3 + q * 4);

    // ---- Sobel column constants ----
    const int cL = (col > 0)   ? col - 1 : 0;
    const int cR = (col < 255) ? col + 1 : 255;
    const float mL = (col > 0)   ? 1.f : 0.f;
    const float mR = (col < 255) ? 1.f : 0.f;

    // ---- prologue: stage rows h0-1..h0+2 (64 units, 8 per wave) ----
#pragma unroll
    for (int k = 0; k < 8; ++k) {
        const int u = wv + 8 * k;                  // 0..63, each once
        STAGE_UNIT(u >> 2, h0 - 1 + (u & 3));
    }

    for (int i = 0; i < 4; ++i) {
        const int r0 = h0 + 2 * i;
        const int r  = r0 + rhalf;
        __syncthreads();   // staged rows complete (barrier drains vmcnt); W2L ready
        const float fv = fmask[((size_t)bb << 16) + (size_t)r * 256 + col];

        // ---- Sobel + pack (thread = (rhalf, col)) ----
        const int sT = (r - 1) & 3, sC = r & 3, sB = (r + 1) & 3;
        unsigned pk[24];
        unsigned carry = 0;
        float selv = 0.f;
#pragma unroll
        for (int c = 0; c < 16; ++c) {
            const float* rT = xs[sT][c];
            const float* rC = xs[sC][c];
            const float* rB = xs[sB][c];
            const float v00 = rT[cL] * mL, v01 = rT[col], v02 = rT[cR] * mR;
            const float v10 = rC[cL] * mL, v11 = rC[col], v12 = rC[cR] * mR;
            const float v20 = rB[cL] * mL, v21 = rB[col], v22 = rB[cR] * mR;
            const float sx = (v02 + 2.f * v12 + v22) - (v00 + 2.f * v10 + v20);
            const float sy = (v20 + 2.f * v21 + v22) - (v00 + 2.f * v01 + v02);
            if (c == 3) {   // exact fp32 3x3 maxpool of alpha (x >= 0 -> zero-pad safe)
                float mx = fmaxf(fmaxf(fmaxf(v00, v01), fmaxf(v02, v10)),
                                 fmaxf(fmaxf(v11, v12), fmaxf(fmaxf(v20, v21), v22)));
                selv = (mx > 0.1f) ? 1.f : 0.f;
            }
            const unsigned ux = f2bf(v11), usx = f2bf(sx), usy = f2bf(sy);
            if ((c & 1) == 0) { pk[(c >> 1) * 3] = ux | (usx << 16); carry = usy; }
            else { pk[(c >> 1) * 3 + 1] = carry | (ux << 16);
                   pk[(c >> 1) * 3 + 2] = usx | (usy << 16); }
        }
        // ---- feats -> wave region (128 B/px, XOR chunk swizzle; sel in chunk 6) ----
        {
            uint4* fb = (uint4*)(region + lane * 128);
            const int sw = lane & 7;
#pragma unroll
            for (int c = 0; c < 6; ++c)
                fb[c ^ sw] = make_uint4(pk[c * 4 + 0], pk[c * 4 + 1], pk[c * 4 + 2], pk[c * 4 + 3]);
            *(float*)(fb + (6 ^ sw)) = (fv != 0.f) ? selv : 0.f;
        }
        // ---- preload all 4 subs' B-frags + sel to regs (region becomes H/bounce) ----
        bf16x8 Bk0[4], Bk1[4];
        float sv[4];
        const int rsw = ln & 7;
#pragma unroll
        for (int s = 0; s < 4; ++s) {
            const char* fp = region + (s * 16 + ln) * 128;
            Bk0[s] = *(const bf16x8*)(fp + ((q ^ rsw) << 4));
            bf16x8 t1 = {};
            if (q < 2)       t1 = *(const bf16x8*)(fp + (((4 + q) ^ rsw) << 4));
            else if (q == 2) t1[0] = (__bf16)1.0f;   // ones column k=48 (bias)
            Bk1[s] = t1;
            sv[s] = *(const float*)(fp + ((6 ^ rsw) << 4));
        }
        __syncthreads();   // all waves done reading xs -> safe to restage oldest slots
        if (i < 3) {       // rows r0+3, r0+4 fly under the MLP phase
#pragma unroll
            for (int k = 0; k < 4; ++k) {
                const int u = wv + 8 * k;          // 0..31, each once
                STAGE_UNIT(u >> 1, r0 + 3 + (u & 1));
            }
        }

        // ---- MLP: 4 subs sequential; single H; W2 A-frags from LDS ----
#pragma unroll
        for (int sub = 0; sub < 4; ++sub) {
            // layer 1 (bias via k=48 column)
#pragma unroll
            for (int mt = 0; mt < 8; ++mt) {
                f32x4 a = {};
                a = __builtin_amdgcn_mfma_f32_16x16x32_bf16(W1f[mt][0], Bk0[sub], a, 0, 0, 0);
                a = __builtin_amdgcn_mfma_f32_16x16x32_bf16(W1f[mt][1], Bk1[sub], a, 0, 0, 0);
                const unsigned r01 = f2bf(fmaxf(a[0], 0.f)) | (f2bf(fmaxf(a[1], 0.f)) << 16);
                const unsigned r23 = f2bf(fmaxf(a[2], 0.f)) | (f2bf(fmaxf(a[3], 0.f)) << 16);
                *(uint2*)(H + ln * 256 + H_SWZ(mt * 2 + (q >> 1), ln) + ((q & 1) << 3))
                    = make_uint2(r01, r23);
            }
            bf16x8 B2[4];
#pragma unroll
            for (int kb = 0; kb < 4; ++kb)
                B2[kb] = *(const bf16x8*)(H + ln * 256 + H_SWZ(kb * 4 + q, ln));
            // layer 2 (W2 A-frags from LDS)
#pragma unroll
            for (int mt = 0; mt < 8; ++mt) {
                f32x4 a = bz2[mt];
#pragma unroll
                for (int kb = 0; kb < 4; ++kb) {
                    const bf16x8 Af = *(const bf16x8*)(W2L + ((mt * 4 + kb) * 64 + lane) * 16);
                    a = __builtin_amdgcn_mfma_f32_16x16x32_bf16(Af, B2[kb], a, 0, 0, 0);
                }
                const unsigned r01 = f2bf(fmaxf(a[0], 0.f)) | (f2bf(fmaxf(a[1], 0.f)) << 16);
                const unsigned r23 = f2bf(fmaxf(a[2], 0.f)) | (f2bf(fmaxf(a[3], 0.f)) << 16);
                *(uint2*)(H + ln * 256 + H_SWZ(mt * 2 + (q >> 1), ln) + ((q & 1) << 3))
                    = make_uint2(r01, r23);
            }
            // layer 3
            f32x4 a3 = bz3;
#pragma unroll
            for (int kb = 0; kb < 4; ++kb) {
                const bf16x8 B3 = *(const bf16x8*)(H + ln * 256 + H_SWZ(kb * 4 + q, ln));
                a3 = __builtin_amdgcn_mfma_f32_16x16x32_bf16(W3f[kb], B3, a3, 0, 0, 0);
            }
            // mask + accumulate into bounce [ch][64 px]
            const float svv = sv[sub];
#pragma unroll
            for (int r4 = 0; r4 < 4; ++r4)
                bounce[(q * 4 + r4) * 64 + sub * 16 + ln] = a3[r4] * svv;
        }
        // ---- stores: per channel, 64 lanes x 4B = full aligned 256 B line ----
        {
            float* orow = out + (((size_t)(bb * 16)) << 16) + (size_t)r * 256
                        + (wv & 3) * 64 + lane;
#pragma unroll
            for (int ch = 0; ch < 16; ++ch)
                orow[(size_t)ch << 16] = bounce[ch * 64 + lane];
        }
    }
}

extern "C" void kernel_launch(void* const* d_in, const int* in_sizes, int n_in,
                              void* d_out, int out_size, void* d_ws, size_t ws_size,
                              hipStream_t stream) {
    (void)in_sizes; (void)n_in; (void)out_size; (void)ws_size;
    const float* x  = (const float*)d_in[0];
    const float* fm = (const float*)d_in[1];
    const float* w1 = (const float*)d_in[2];
    const float* b1 = (const float*)d_in[3];
    const float* w2 = (const float*)d_in[4];
    const float* b2 = (const float*)d_in[5];
    const float* w3 = (const float*)d_in[6];
    const float* b3 = (const float*)d_in[7];
    float* o = (float*)d_out;
    unsigned short* ws = (unsigned short*)d_ws;

    prep_weights<<<dim3(13), dim3(256), 0, stream>>>(w1, b1, w2, w3, ws);

    hipFuncSetAttribute((const void*)fused_kernel,
                        hipFuncAttributeMaxDynamicSharedMemorySize, SM_TOTAL);
    fused_kernel<<<dim3(512), dim3(512), SM_TOTAL, stream>>>(x, fm, ws, b2, b3, o);
}

// Round 6
// 313.648 us; speedup vs baseline: 1.0064x; 1.0064x over previous
//
#include <hip/hip_runtime.h>

// Round 9: spill fix, take 2.
//   R7/R8 both compiled to VGPR_Count=128 with ~100 MB of scratch spill traffic
//   in FETCH and WRITE. Root cause: dynamic LDS is invisible to the allocator,
//   so it targets 4 waves/SIMD (128 regs) although LDS pins 2 waves/SIMD.
//   Fix: amdgpu_waves_per_eu(2,2) — min=2 caps at 256, max=2 stops the
//   allocator from squeezing to 128. Everything else identical to R8.

#define NPX (1u << 20)

using bf16x8 = __attribute__((ext_vector_type(8))) __bf16;
using f32x4  = __attribute__((ext_vector_type(4))) float;

__device__ __forceinline__ unsigned f2bf(float f) {
    unsigned u = __float_as_uint(f);
    u += 0x7fffu + ((u >> 16) & 1u);   // RNE; inputs finite
    return u >> 16;
}

// ---- ws layout (ushort offsets): weight frags only ----
#define WS1_OFF 0        // [mt=8][kb=2][lane=64][8]  A-frags of W1^T (K-pad 48->64; k=48 = b1)
#define WS2_OFF 8192     // [mt=8][kb=4][lane=64][8]  A-frags of W2^T
#define WS3_OFF 24576    // [kb=4][lane=64][8]        A-frags of W3^T

__global__ __launch_bounds__(256)
void prep_weights(const float* __restrict__ w1, const float* __restrict__ b1,
                  const float* __restrict__ w2, const float* __restrict__ w3,
                  unsigned short* __restrict__ ws) {
    const int gid = blockIdx.x * 256 + threadIdx.x;   // 13 blocks x 256 = 3328 slots
    if (gid < 1024) {   // ws1 (feature order k = 3*c + t; w1 row = t*16 + c; k=48 -> b1)
        const int s = gid;
        const int mt = s >> 7, kb = (s >> 6) & 1, lane = s & 63;
        const int q = lane >> 4, ln = lane & 15;
#pragma unroll
        for (int j = 0; j < 8; ++j) {
            const int k = kb * 32 + q * 8 + j;
            float val = 0.f;
            if (k < 48) { const int c = k / 3, t = k - 3 * c; val = w1[(t * 16 + c) * 128 + mt * 16 + ln]; }
            else if (k == 48) val = b1[mt * 16 + ln];   // bias column (B side supplies 1.0)
            ws[WS1_OFF + s * 8 + j] = (unsigned short)f2bf(val);
        }
    } else if (gid < 3072) {   // ws2
        const int s2 = gid - 1024;
        const int mt = s2 >> 8, kb = (s2 >> 6) & 3, lane = s2 & 63;
        const int q = lane >> 4, ln = lane & 15;
#pragma unroll
        for (int j = 0; j < 8; ++j) {
            const int k = kb * 32 + q * 8 + j;
            ws[WS2_OFF + s2 * 8 + j] = (unsigned short)f2bf(w2[k * 128 + mt * 16 + ln]);
        }
    } else if (gid < 3328) {   // ws3
        const int s3 = gid - 3072;
        const int kb = s3 >> 6, lane = s3 & 63;
        const int q = lane >> 4, ln = lane & 15;
#pragma unroll
        for (int j = 0; j < 8; ++j) {
            const int k = kb * 32 + q * 8 + j;
            ws[WS3_OFF + s3 * 8 + j] = (unsigned short)f2bf(w3[k * 16 + ln]);
        }
    }
}

// ===================== fused kernel =====================
// 512 blocks = 16 batches x 32 strips of 8 rows; 512 threads = 8 waves.
// Iteration i covers rows r0=h0+2i, r0+1: waves 0-3 -> row r0 (cols 64w..),
// waves 4-7 -> row r0+1. Wave w's region holds feats/H for its own 64-px tile.

// LDS layout (bytes), total 163840 (full pool, 1 block/CU, 8 waves = 2/SIMD):
#define SM_XS    0       // float xs[4][16][256] rolling row window   = 65536
#define SM_W2    65536   // W2 A-frags (also W1/W3 bounce at init)    = 32768
#define SM_WR    98304   // 8 wave regions x 8192                     = 65536
#define SM_TOTAL 163840

#define H_SWZ(j, ln) ((((j) ^ ((ln) & 7)) << 4))

#define GLDS16(gp, lp) __builtin_amdgcn_global_load_lds(                     \
    (const __attribute__((address_space(1))) void*)(gp),                     \
    (__attribute__((address_space(3))) void*)(lp), 16, 0, 0)

// stage one (ch,row) pair -> xs[row&3][ch][*]; row/ch wave-uniform.
// dest = wave-uniform base + lane*16 (global_load_lds semantics); OOB rows zero-fill.
#define STAGE_UNIT(chv, rowv) do {                                           \
        const int _sl = (rowv) & 3;                                          \
        char* _ld = smem + SM_XS + (size_t)(((_sl) * 16 + (chv)) * 256) * 4; \
        if ((unsigned)(rowv) < 256u) {                                       \
            const float* _gs = xb + ((size_t)(chv) << 16)                    \
                             + (size_t)(unsigned)(rowv) * 256 + lane * 4;    \
            GLDS16(_gs, _ld);                                                \
        } else {                                                             \
            *(float4*)(_ld + lane * 16) = make_float4(0.f, 0.f, 0.f, 0.f);   \
        } } while (0)

extern "C" __global__ __launch_bounds__(512)
__attribute__((amdgpu_waves_per_eu(2, 2)))
void fused_kernel(const float* __restrict__ x, const float* __restrict__ fmask,
                  const unsigned short* __restrict__ wf,
                  const float* __restrict__ b2, const float* __restrict__ b3,
                  float* __restrict__ out) {
    extern __shared__ char smem[];
    float (*xs)[16][256] = (float (*)[16][256])(smem + SM_XS);
    char* W2L = smem + SM_W2;

    const int t = threadIdx.x;
    const int wv = t >> 6, lane = t & 63;
    const int q = lane >> 4, ln = lane & 15;
    const int rhalf = t >> 8;              // 0: waves 0-3, 1: waves 4-7
    const int col = t & 255;
    char* region = smem + SM_WR + wv * 8192;   // feats phase / H + bounce in MLP phase
    char* H = region;                          // 4096 B
    float* bounce = (float*)(region + 4096);   // [16 ch][64 px] = 4096 B

    const int bb = blockIdx.x >> 5;
    const int h0 = (blockIdx.x & 31) << 3;
    const float* xb = x + ((size_t)bb << 20);

    // ---- stage W1/W3 frag tables through LDS (ws read once per block) ----
    {
        const uint4* s1 = (const uint4*)(wf + WS1_OFF);   // 1024 uint4 = 16 KB
        uint4* dW = (uint4*)W2L;
        dW[t]       = s1[t];
        dW[t + 512] = s1[t + 512];
        if (t < 256) dW[1024 + t] = ((const uint4*)(wf + WS3_OFF))[t];   // 4 KB
    }
    __syncthreads();
    bf16x8 W1f[8][2], W3f[4];
#pragma unroll
    for (int mt = 0; mt < 8; ++mt) {
        W1f[mt][0] = *(const bf16x8*)(W2L + ((mt * 2 + 0) * 64 + lane) * 16);
        W1f[mt][1] = *(const bf16x8*)(W2L + ((mt * 2 + 1) * 64 + lane) * 16);
    }
#pragma unroll
    for (int kb = 0; kb < 4; ++kb)
        W3f[kb] = *(const bf16x8*)(W2L + 16384 + (kb * 64 + lane) * 16);
    __syncthreads();
    {   // now stage W2 frags (overwrites the bounce area)
        const uint4* s2 = (const uint4*)(wf + WS2_OFF);   // 2048 uint4 = 32 KB
        uint4* dW = (uint4*)W2L;
#pragma unroll
        for (int i2 = 0; i2 < 4; ++i2) dW[t + i2 * 512] = s2[t + i2 * 512];
    }
    // ---- biases -> VGPRs (loop-invariant) ----
    f32x4 bz2[8];
#pragma unroll
    for (int mt = 0; mt < 8; ++mt) bz2[mt] = *(const f32x4*)(b2 + mt * 16 + q * 4);
    const f32x4 bz3 = *(const f32x4*)(b3 + q * 4);

    // ---- Sobel column constants ----
    const int cL = (col > 0)   ? col - 1 : 0;
    const int cR = (col < 255) ? col + 1 : 255;
    const float mL = (col > 0)   ? 1.f : 0.f;
    const float mR = (col < 255) ? 1.f : 0.f;

    // ---- prologue: stage rows h0-1..h0+2 (64 units, 8 per wave) ----
#pragma unroll
    for (int k = 0; k < 8; ++k) {
        const int u = wv + 8 * k;                  // 0..63, each once
        STAGE_UNIT(u >> 2, h0 - 1 + (u & 3));
    }

    for (int i = 0; i < 4; ++i) {
        const int r0 = h0 + 2 * i;
        const int r  = r0 + rhalf;
        __syncthreads();   // staged rows complete (barrier drains vmcnt); W2L ready
        const float fv = fmask[((size_t)bb << 16) + (size_t)r * 256 + col];

        // ---- Sobel + pack (thread = (rhalf, col)) ----
        const int sT = (r - 1) & 3, sC = r & 3, sB = (r + 1) & 3;
        unsigned pk[24];
        unsigned carry = 0;
        float selv = 0.f;
#pragma unroll
        for (int c = 0; c < 16; ++c) {
            const float* rT = xs[sT][c];
            const float* rC = xs[sC][c];
            const float* rB = xs[sB][c];
            const float v00 = rT[cL] * mL, v01 = rT[col], v02 = rT[cR] * mR;
            const float v10 = rC[cL] * mL, v11 = rC[col], v12 = rC[cR] * mR;
            const float v20 = rB[cL] * mL, v21 = rB[col], v22 = rB[cR] * mR;
            const float sx = (v02 + 2.f * v12 + v22) - (v00 + 2.f * v10 + v20);
            const float sy = (v20 + 2.f * v21 + v22) - (v00 + 2.f * v01 + v02);
            if (c == 3) {   // exact fp32 3x3 maxpool of alpha (x >= 0 -> zero-pad safe)
                float mx = fmaxf(fmaxf(fmaxf(v00, v01), fmaxf(v02, v10)),
                                 fmaxf(fmaxf(v11, v12), fmaxf(fmaxf(v20, v21), v22)));
                selv = (mx > 0.1f) ? 1.f : 0.f;
            }
            const unsigned ux = f2bf(v11), usx = f2bf(sx), usy = f2bf(sy);
            if ((c & 1) == 0) { pk[(c >> 1) * 3] = ux | (usx << 16); carry = usy; }
            else { pk[(c >> 1) * 3 + 1] = carry | (ux << 16);
                   pk[(c >> 1) * 3 + 2] = usx | (usy << 16); }
        }
        // ---- feats -> wave region (128 B/px, XOR chunk swizzle; sel in chunk 6) ----
        {
            uint4* fb = (uint4*)(region + lane * 128);
            const int sw = lane & 7;
#pragma unroll
            for (int c = 0; c < 6; ++c)
                fb[c ^ sw] = make_uint4(pk[c * 4 + 0], pk[c * 4 + 1], pk[c * 4 + 2], pk[c * 4 + 3]);
            *(float*)(fb + (6 ^ sw)) = (fv != 0.f) ? selv : 0.f;
        }
        // ---- preload all 4 subs' B-frags + sel to regs (region becomes H/bounce) ----
        bf16x8 Bk0[4], Bk1[4];
        float sv[4];
        const int rsw = ln & 7;
#pragma unroll
        for (int s = 0; s < 4; ++s) {
            const char* fp = region + (s * 16 + ln) * 128;
            Bk0[s] = *(const bf16x8*)(fp + ((q ^ rsw) << 4));
            bf16x8 t1 = {};
            if (q < 2)       t1 = *(const bf16x8*)(fp + (((4 + q) ^ rsw) << 4));
            else if (q == 2) t1[0] = (__bf16)1.0f;   // ones column k=48 (bias)
            Bk1[s] = t1;
            sv[s] = *(const float*)(fp + ((6 ^ rsw) << 4));
        }
        __syncthreads();   // all waves done reading xs -> safe to restage oldest slots
        if (i < 3) {       // rows r0+3, r0+4 fly under the MLP phase
#pragma unroll
            for (int k = 0; k < 4; ++k) {
                const int u = wv + 8 * k;          // 0..31, each once
                STAGE_UNIT(u >> 1, r0 + 3 + (u & 1));
            }
        }

        // ---- MLP: 4 subs sequential; single H; W2 A-frags from LDS ----
#pragma unroll
        for (int sub = 0; sub < 4; ++sub) {
            // layer 1 (bias via k=48 column)
#pragma unroll
            for (int mt = 0; mt < 8; ++mt) {
                f32x4 a = {};
                a = __builtin_amdgcn_mfma_f32_16x16x32_bf16(W1f[mt][0], Bk0[sub], a, 0, 0, 0);
                a = __builtin_amdgcn_mfma_f32_16x16x32_bf16(W1f[mt][1], Bk1[sub], a, 0, 0, 0);
                const unsigned r01 = f2bf(fmaxf(a[0], 0.f)) | (f2bf(fmaxf(a[1], 0.f)) << 16);
                const unsigned r23 = f2bf(fmaxf(a[2], 0.f)) | (f2bf(fmaxf(a[3], 0.f)) << 16);
                *(uint2*)(H + ln * 256 + H_SWZ(mt * 2 + (q >> 1), ln) + ((q & 1) << 3))
                    = make_uint2(r01, r23);
            }
            bf16x8 B2[4];
#pragma unroll
            for (int kb = 0; kb < 4; ++kb)
                B2[kb] = *(const bf16x8*)(H + ln * 256 + H_SWZ(kb * 4 + q, ln));
            // layer 2 (W2 A-frags from LDS)
#pragma unroll
            for (int mt = 0; mt < 8; ++mt) {
                f32x4 a = bz2[mt];
#pragma unroll
                for (int kb = 0; kb < 4; ++kb) {
                    const bf16x8 Af = *(const bf16x8*)(W2L + ((mt * 4 + kb) * 64 + lane) * 16);
                    a = __builtin_amdgcn_mfma_f32_16x16x32_bf16(Af, B2[kb], a, 0, 0, 0);
                }
                const unsigned r01 = f2bf(fmaxf(a[0], 0.f)) | (f2bf(fmaxf(a[1], 0.f)) << 16);
                const unsigned r23 = f2bf(fmaxf(a[2], 0.f)) | (f2bf(fmaxf(a[3], 0.f)) << 16);
                *(uint2*)(H + ln * 256 + H_SWZ(mt * 2 + (q >> 1), ln) + ((q & 1) << 3))
                    = make_uint2(r01, r23);
            }
            // layer 3
            f32x4 a3 = bz3;
#pragma unroll
            for (int kb = 0; kb < 4; ++kb) {
                const bf16x8 B3 = *(const bf16x8*)(H + ln * 256 + H_SWZ(kb * 4 + q, ln));
                a3 = __builtin_amdgcn_mfma_f32_16x16x32_bf16(W3f[kb], B3, a3, 0, 0, 0);
            }
            // mask + accumulate into bounce [ch][64 px]
            const float svv = sv[sub];
#pragma unroll
            for (int r4 = 0; r4 < 4; ++r4)
                bounce[(q * 4 + r4) * 64 + sub * 16 + ln] = a3[r4] * svv;
        }
        // ---- stores: per channel, 64 lanes x 4B = full aligned 256 B line ----
        {
            float* orow = out + (((size_t)(bb * 16)) << 16) + (size_t)r * 256
                        + (wv & 3) * 64 + lane;
#pragma unroll
            for (int ch = 0; ch < 16; ++ch)
                orow[(size_t)ch << 16] = bounce[ch * 64 + lane];
        }
    }
}

extern "C" void kernel_launch(void* const* d_in, const int* in_sizes, int n_in,
                              void* d_out, int out_size, void* d_ws, size_t ws_size,
                              hipStream_t stream) {
    (void)in_sizes; (void)n_in; (void)out_size; (void)ws_size;
    const float* x  = (const float*)d_in[0];
    const float* fm = (const float*)d_in[1];
    const float* w1 = (const float*)d_in[2];
    const float* b1 = (const float*)d_in[3];
    const float* w2 = (const float*)d_in[4];
    const float* b2 = (const float*)d_in[5];
    const float* w3 = (const float*)d_in[6];
    const float* b3 = (const float*)d_in[7];
    float* o = (float*)d_out;
    unsigned short* ws = (unsigned short*)d_ws;

    prep_weights<<<dim3(13), dim3(256), 0, stream>>>(w1, b1, w2, w3, ws);

    hipFuncSetAttribute((const void*)fused_kernel,
                        hipFuncAttributeMaxDynamicSharedMemorySize, SM_TOTAL);
    fused_kernel<<<dim3(512), dim3(512), SM_TOTAL, stream>>>(x, fm, ws, b2, b3, o);
}

// Round 7
// 259.516 us; speedup vs baseline: 1.2163x; 1.2086x over previous
//
#include <hip/hip_runtime.h>

// Round 10: fit 128 VGPRs for real (R7-R9 all spilled ~23 regs/thread-iter;
// allocator pins 128 regardless of hints since dynamic LDS is invisible).
//   - W3 frags + b2/b3 biases -> LDS tables (AUX, 4.7KB)  [-52 regs]
//   - feats packed 112B/px (7 chunks, rotate-7 swizzle, sel in chunk 6)
//     -> regions 7KB, frees 8KB for AUX
//   - H 4KB -> 2KB via two-phase layers (mt 0-3 then 4-7; in-order DS)
//   - per-PAIR Bk preload (H lives in the pair's freed feats slots) [-23 regs]
//   - bounce (132B rows) overwrites dead H; full 256B line stores kept
// Structure otherwise = R8: 512 thr, 2 rows/iter, GLDS x-staging, W2 in LDS.

using bf16x8 = __attribute__((ext_vector_type(8))) __bf16;
using f32x4  = __attribute__((ext_vector_type(4))) float;

__device__ __forceinline__ unsigned f2bf(float f) {
    unsigned u = __float_as_uint(f);
    u += 0x7fffu + ((u >> 16) & 1u);   // RNE; inputs finite
    return u >> 16;
}

// ---- ws layout (ushort offsets): weight frags only ----
#define WS1_OFF 0        // [mt=8][kb=2][lane=64][8]  A-frags of W1^T (k=48 = b1)
#define WS2_OFF 8192     // [mt=8][kb=4][lane=64][8]  A-frags of W2^T
#define WS3_OFF 24576    // [kb=4][lane=64][8]        A-frags of W3^T

__global__ __launch_bounds__(256)
void prep_weights(const float* __restrict__ w1, const float* __restrict__ b1,
                  const float* __restrict__ w2, const float* __restrict__ w3,
                  unsigned short* __restrict__ ws) {
    const int gid = blockIdx.x * 256 + threadIdx.x;   // 13 blocks x 256 = 3328 slots
    if (gid < 1024) {   // ws1 (feature order k = 3*c + t; w1 row = t*16 + c; k=48 -> b1)
        const int s = gid;
        const int mt = s >> 7, kb = (s >> 6) & 1, lane = s & 63;
        const int q = lane >> 4, ln = lane & 15;
#pragma unroll
        for (int j = 0; j < 8; ++j) {
            const int k = kb * 32 + q * 8 + j;
            float val = 0.f;
            if (k < 48) { const int c = k / 3, t = k - 3 * c; val = w1[(t * 16 + c) * 128 + mt * 16 + ln]; }
            else if (k == 48) val = b1[mt * 16 + ln];   // bias column (B side supplies 1.0)
            ws[WS1_OFF + s * 8 + j] = (unsigned short)f2bf(val);
        }
    } else if (gid < 3072) {   // ws2
        const int s2 = gid - 1024;
        const int mt = s2 >> 8, kb = (s2 >> 6) & 3, lane = s2 & 63;
        const int q = lane >> 4, ln = lane & 15;
#pragma unroll
        for (int j = 0; j < 8; ++j) {
            const int k = kb * 32 + q * 8 + j;
            ws[WS2_OFF + s2 * 8 + j] = (unsigned short)f2bf(w2[k * 128 + mt * 16 + ln]);
        }
    } else if (gid < 3328) {   // ws3
        const int s3 = gid - 3072;
        const int kb = s3 >> 6, lane = s3 & 63;
        const int q = lane >> 4, ln = lane & 15;
#pragma unroll
        for (int j = 0; j < 8; ++j) {
            const int k = kb * 32 + q * 8 + j;
            ws[WS3_OFF + s3 * 8 + j] = (unsigned short)f2bf(w3[k * 16 + ln]);
        }
    }
}

// ===================== fused kernel =====================
// 512 blocks = 16 batches x 32 strips of 8 rows; 512 threads = 8 waves.
// Iteration i: waves 0-3 -> row r0, waves 4-7 -> row r0+1 (64 px per wave).

// LDS layout (bytes), total 160320 <= 163840 (1 block/CU, 8 waves = 2/SIMD):
#define SM_XS    0        // float xs[4][16][256] rolling row window  = 65536
#define SM_W2    65536    // W2 A-frags (also W1 bounce at init)      = 32768
#define SM_WR    98304    // 8 wave regions x 7168 (64px x 112B)      = 57344
#define SM_AUX   155648   // W3 A-frags                               = 4096
#define SM_B2L   159744   // b2[128] f32                              = 512
#define SM_B3L   160256   // b3[16] f32                               = 64
#define SM_TOTAL 160320

#define GLDS16(gp, lp) __builtin_amdgcn_global_load_lds(                     \
    (const __attribute__((address_space(1))) void*)(gp),                     \
    (__attribute__((address_space(3))) void*)(lp), 16, 0, 0)

// stage one (ch,row) pair -> xs[row&3][ch][*]; row/ch wave-uniform.
#define STAGE_UNIT(chv, rowv) do {                                           \
        const int _sl = (rowv) & 3;                                          \
        char* _ld = smem + SM_XS + (size_t)(((_sl) * 16 + (chv)) * 256) * 4; \
        if ((unsigned)(rowv) < 256u) {                                       \
            const float* _gs = xb + ((size_t)(chv) << 16)                    \
                             + (size_t)(unsigned)(rowv) * 256 + lane * 4;    \
            GLDS16(_gs, _ld);                                                \
        } else {                                                             \
            *(float4*)(_ld + lane * 16) = make_float4(0.f, 0.f, 0.f, 0.f);   \
        } } while (0)

// H chunk swizzle: j in 0..7, row = ln (16 rows x 128B)
#define HCH(j) ((((j) ^ (ln & 7)) << 4))

extern "C" __global__ __launch_bounds__(512)
void fused_kernel(const float* __restrict__ x, const float* __restrict__ fmask,
                  const unsigned short* __restrict__ wf,
                  const float* __restrict__ b2, const float* __restrict__ b3,
                  float* __restrict__ out) {
    extern __shared__ char smem[];
    float (*xs)[16][256] = (float (*)[16][256])(smem + SM_XS);
    char* W2L = smem + SM_W2;

    const int t = threadIdx.x;
    const int wv = t >> 6, lane = t & 63;
    const int q = lane >> 4, ln = lane & 15;
    const int rhalf = t >> 8;              // 0: waves 0-3, 1: waves 4-7
    const int col = t & 255;
    char* region = smem + SM_WR + wv * 7168;   // this wave's 64px feats/H/bounce

    const int bb = blockIdx.x >> 5;
    const int h0 = (blockIdx.x & 31) << 3;
    const float* xb = x + ((size_t)bb << 20);

    // ---- init staging: W1 via W2L bounce; W3/b2/b3 -> AUX ----
    {
        const uint4* s1 = (const uint4*)(wf + WS1_OFF);   // 16 KB
        uint4* dW = (uint4*)W2L;
        dW[t]       = s1[t];
        dW[t + 512] = s1[t + 512];
        if (t < 256) ((uint4*)(smem + SM_AUX))[t] = ((const uint4*)(wf + WS3_OFF))[t];
        if (t < 128) ((float*)(smem + SM_B2L))[t] = b2[t];
        if (t < 16)  ((float*)(smem + SM_B3L))[t] = b3[t];
    }
    __syncthreads();
    bf16x8 W1f[8][2];
#pragma unroll
    for (int mt = 0; mt < 8; ++mt) {
        W1f[mt][0] = *(const bf16x8*)(W2L + ((mt * 2 + 0) * 64 + lane) * 16);
        W1f[mt][1] = *(const bf16x8*)(W2L + ((mt * 2 + 1) * 64 + lane) * 16);
    }
    __syncthreads();
    {   // stage W2 frags (overwrites bounce area)
        const uint4* s2 = (const uint4*)(wf + WS2_OFF);   // 32 KB
        uint4* dW = (uint4*)W2L;
#pragma unroll
        for (int i2 = 0; i2 < 4; ++i2) dW[t + i2 * 512] = s2[t + i2 * 512];
    }

    // ---- Sobel column constants ----
    const int cL = (col > 0)   ? col - 1 : 0;
    const int cR = (col < 255) ? col + 1 : 255;
    const float mL = (col > 0)   ? 1.f : 0.f;
    const float mR = (col < 255) ? 1.f : 0.f;
    const int m7w = lane % 7;          // write-side rotate
    const int lq7 = ln % 7;            // read-side rotate base

    // ---- prologue: stage rows h0-1..h0+2 (64 units, 8 per wave) ----
#pragma unroll
    for (int k = 0; k < 8; ++k) {
        const int u = wv + 8 * k;
        STAGE_UNIT(u >> 2, h0 - 1 + (u & 3));
    }

    for (int i = 0; i < 4; ++i) {
        const int r0 = h0 + 2 * i;
        const int r  = r0 + rhalf;
        __syncthreads();   // staged rows complete; W2L ready (iter 0)
        const float fv = fmask[((size_t)bb << 16) + (size_t)r * 256 + col];

        // ---- Sobel + pack (thread = (rhalf, col)) ----
        const int sT = (r - 1) & 3, sC = r & 3, sB = (r + 1) & 3;
        unsigned pk[24];
        unsigned carry = 0;
        float selv = 0.f;
#pragma unroll
        for (int c = 0; c < 16; ++c) {
            const float* rT = xs[sT][c];
            const float* rC = xs[sC][c];
            const float* rB = xs[sB][c];
            const float v00 = rT[cL] * mL, v01 = rT[col], v02 = rT[cR] * mR;
            const float v10 = rC[cL] * mL, v11 = rC[col], v12 = rC[cR] * mR;
            const float v20 = rB[cL] * mL, v21 = rB[col], v22 = rB[cR] * mR;
            const float sx = (v02 + 2.f * v12 + v22) - (v00 + 2.f * v10 + v20);
            const float sy = (v20 + 2.f * v21 + v22) - (v00 + 2.f * v01 + v02);
            if (c == 3) {   // exact fp32 3x3 maxpool of alpha (x >= 0 -> zero-pad safe)
                float mx = fmaxf(fmaxf(fmaxf(v00, v01), fmaxf(v02, v10)),
                                 fmaxf(fmaxf(v11, v12), fmaxf(fmaxf(v20, v21), v22)));
                selv = (mx > 0.1f) ? 1.f : 0.f;
            }
            const unsigned ux = f2bf(v11), usx = f2bf(sx), usy = f2bf(sy);
            if ((c & 1) == 0) { pk[(c >> 1) * 3] = ux | (usx << 16); carry = usy; }
            else { pk[(c >> 1) * 3 + 1] = carry | (ux << 16);
                   pk[(c >> 1) * 3 + 2] = usx | (usy << 16); }
        }
        // ---- feats -> wave region: 7 chunks x 16B, rotate-7; sel in chunk 6 ----
        {
            char* fb = region + lane * 112;
#pragma unroll
            for (int c = 0; c < 6; ++c) {
                int pc = c + m7w; if (pc >= 7) pc -= 7;
                *(uint4*)(fb + pc * 16)
                    = make_uint4(pk[c * 4 + 0], pk[c * 4 + 1], pk[c * 4 + 2], pk[c * 4 + 3]);
            }
            const int pc6 = (m7w == 0) ? 6 : (m7w - 1);
            *(float*)(fb + pc6 * 16) = (fv != 0.f) ? selv : 0.f;
        }
        __syncthreads();   // all waves done reading xs -> safe to restage
        if (i < 3) {       // rows r0+3, r0+4 fly under the MLP phase
#pragma unroll
            for (int k = 0; k < 4; ++k) {
                const int u = wv + 8 * k;
                STAGE_UNIT(u >> 1, r0 + 3 + (u & 1));
            }
        }

        // ---- MLP: 2 pairs; H(2KB two-phase) + bounce overlay the pair's slots ----
#pragma unroll
        for (int p = 0; p < 2; ++p) {
            char* Hb = region + p * 3584;
            // preload this pair's B-frags + sel (frees slots 2p, 2p+1)
            bf16x8 Bk0a[2], Bk1a[2];
            float sva[2];
#pragma unroll
            for (int s2 = 0; s2 < 2; ++s2) {
                const int s = p * 2 + s2;
                int v7 = 2 * s + lq7; if (v7 >= 7) v7 -= 7;   // px % 7
                const char* fp = region + (s * 16 + ln) * 112;
                int c0 = q + v7; if (c0 >= 7) c0 -= 7;
                Bk0a[s2] = *(const bf16x8*)(fp + c0 * 16);
                bf16x8 t1 = {};
                if (q < 2) { int c1 = 4 + q + v7; if (c1 >= 7) c1 -= 7;
                             t1 = *(const bf16x8*)(fp + c1 * 16); }
                else if (q == 2) t1[0] = (__bf16)1.0f;   // ones column k=48 (bias)
                Bk1a[s2] = t1;
                const int c6 = (v7 == 0) ? 6 : (v7 - 1);
                sva[s2] = *(const float*)(fp + c6 * 16);
            }
            f32x4 a3h;
#pragma unroll
            for (int s2 = 0; s2 < 2; ++s2) {
                // ---- layer 1, phase A (mt 0-3) ----
                bf16x8 B2[4];
#pragma unroll
                for (int m = 0; m < 4; ++m) {
                    f32x4 a = {};
                    a = __builtin_amdgcn_mfma_f32_16x16x32_bf16(W1f[m][0], Bk0a[s2], a, 0, 0, 0);
                    a = __builtin_amdgcn_mfma_f32_16x16x32_bf16(W1f[m][1], Bk1a[s2], a, 0, 0, 0);
                    const unsigned r01 = f2bf(fmaxf(a[0], 0.f)) | (f2bf(fmaxf(a[1], 0.f)) << 16);
                    const unsigned r23 = f2bf(fmaxf(a[2], 0.f)) | (f2bf(fmaxf(a[3], 0.f)) << 16);
                    *(uint2*)(Hb + ln * 128 + HCH(m * 2 + (q >> 1)) + ((q & 1) << 3))
                        = make_uint2(r01, r23);
                }
                B2[0] = *(const bf16x8*)(Hb + ln * 128 + HCH(q));
                B2[1] = *(const bf16x8*)(Hb + ln * 128 + HCH(4 + q));
                // ---- layer 1, phase B (mt 4-7, same 2KB) ----
#pragma unroll
                for (int m = 4; m < 8; ++m) {
                    f32x4 a = {};
                    a = __builtin_amdgcn_mfma_f32_16x16x32_bf16(W1f[m][0], Bk0a[s2], a, 0, 0, 0);
                    a = __builtin_amdgcn_mfma_f32_16x16x32_bf16(W1f[m][1], Bk1a[s2], a, 0, 0, 0);
                    const unsigned r01 = f2bf(fmaxf(a[0], 0.f)) | (f2bf(fmaxf(a[1], 0.f)) << 16);
                    const unsigned r23 = f2bf(fmaxf(a[2], 0.f)) | (f2bf(fmaxf(a[3], 0.f)) << 16);
                    *(uint2*)(Hb + ln * 128 + HCH((m - 4) * 2 + (q >> 1)) + ((q & 1) << 3))
                        = make_uint2(r01, r23);
                }
                B2[2] = *(const bf16x8*)(Hb + ln * 128 + HCH(q));
                B2[3] = *(const bf16x8*)(Hb + ln * 128 + HCH(4 + q));
                // ---- layer 2, phase A (mt 0-3; bias from LDS) ----
                bf16x8 B3[4];
#pragma unroll
                for (int m = 0; m < 4; ++m) {
                    f32x4 a = *(const f32x4*)(smem + SM_B2L + m * 64 + q * 16);
#pragma unroll
                    for (int kb = 0; kb < 4; ++kb) {
                        const bf16x8 Af = *(const bf16x8*)(W2L + ((m * 4 + kb) * 64 + lane) * 16);
                        a = __builtin_amdgcn_mfma_f32_16x16x32_bf16(Af, B2[kb], a, 0, 0, 0);
                    }
                    const unsigned r01 = f2bf(fmaxf(a[0], 0.f)) | (f2bf(fmaxf(a[1], 0.f)) << 16);
                    const unsigned r23 = f2bf(fmaxf(a[2], 0.f)) | (f2bf(fmaxf(a[3], 0.f)) << 16);
                    *(uint2*)(Hb + ln * 128 + HCH(m * 2 + (q >> 1)) + ((q & 1) << 3))
                        = make_uint2(r01, r23);
                }
                B3[0] = *(const bf16x8*)(Hb + ln * 128 + HCH(q));
                B3[1] = *(const bf16x8*)(Hb + ln * 128 + HCH(4 + q));
                // ---- layer 2, phase B (mt 4-7) ----
#pragma unroll
                for (int m = 4; m < 8; ++m) {
                    f32x4 a = *(const f32x4*)(smem + SM_B2L + m * 64 + q * 16);
#pragma unroll
                    for (int kb = 0; kb < 4; ++kb) {
                        const bf16x8 Af = *(const bf16x8*)(W2L + ((m * 4 + kb) * 64 + lane) * 16);
                        a = __builtin_amdgcn_mfma_f32_16x16x32_bf16(Af, B2[kb], a, 0, 0, 0);
                    }
                    const unsigned r01 = f2bf(fmaxf(a[0], 0.f)) | (f2bf(fmaxf(a[1], 0.f)) << 16);
                    const unsigned r23 = f2bf(fmaxf(a[2], 0.f)) | (f2bf(fmaxf(a[3], 0.f)) << 16);
                    *(uint2*)(Hb + ln * 128 + HCH((m - 4) * 2 + (q >> 1)) + ((q & 1) << 3))
                        = make_uint2(r01, r23);
                }
                B3[2] = *(const bf16x8*)(Hb + ln * 128 + HCH(q));
                B3[3] = *(const bf16x8*)(Hb + ln * 128 + HCH(4 + q));
                // ---- layer 3 (W3 frags + bias from LDS) ----
                f32x4 a3 = *(const f32x4*)(smem + SM_B3L + q * 16);
#pragma unroll
                for (int kb = 0; kb < 4; ++kb) {
                    const bf16x8 W3a = *(const bf16x8*)(smem + SM_AUX + (kb * 64 + lane) * 16);
                    a3 = __builtin_amdgcn_mfma_f32_16x16x32_bf16(W3a, B3[kb], a3, 0, 0, 0);
                }
                const float svv = sva[s2];
#pragma unroll
                for (int r4 = 0; r4 < 4; ++r4) a3[r4] *= svv;
                if (s2 == 0) a3h = a3;
                else {   // H dead -> write pair bounce [ch][2x16px], 132B rows
#pragma unroll
                    for (int r4 = 0; r4 < 4; ++r4) {
                        *(float*)(Hb + (q * 4 + r4) * 132 + ln * 4)      = a3h[r4];
                        *(float*)(Hb + (q * 4 + r4) * 132 + 64 + ln * 4) = a3[r4];
                    }
                }
            }
        }
        // ---- stores: per channel, 64 lanes x 4B = full aligned 256 B line ----
        {
            float* orow = out + (((size_t)(bb * 16)) << 16) + (size_t)r * 256
                        + (wv & 3) * 64 + lane;
#pragma unroll
            for (int ch = 0; ch < 16; ++ch) {
                const float v = *(const float*)(region + (lane >> 5) * 3584
                              + ch * 132 + ((lane >> 4) & 1) * 64 + (lane & 15) * 4);
                orow[(size_t)ch << 16] = v;
            }
        }
    }
}

extern "C" void kernel_launch(void* const* d_in, const int* in_sizes, int n_in,
                              void* d_out, int out_size, void* d_ws, size_t ws_size,
                              hipStream_t stream) {
    (void)in_sizes; (void)n_in; (void)out_size; (void)ws_size;
    const float* x  = (const float*)d_in[0];
    const float* fm = (const float*)d_in[1];
    const float* w1 = (const float*)d_in[2];
    const float* b1 = (const float*)d_in[3];
    const float* w2 = (const float*)d_in[4];
    const float* b2 = (const float*)d_in[5];
    const float* w3 = (const float*)d_in[6];
    const float* b3 = (const float*)d_in[7];
    float* o = (float*)d_out;
    unsigned short* ws = (unsigned short*)d_ws;

    prep_weights<<<dim3(13), dim3(256), 0, stream>>>(w1, b1, w2, w3, ws);

    hipFuncSetAttribute((const void*)fused_kernel,
                        hipFuncAttributeMaxDynamicSharedMemorySize, SM_TOTAL);
    fused_kernel<<<dim3(512), dim3(512), SM_TOTAL, stream>>>(x, fm, ws, b2, b3, o);
}

// Round 8
// 220.886 us; speedup vs baseline: 1.4290x; 1.1749x over previous
//
#include <hip/hip_runtime.h>

// Round 11: R10 structure + three fixes.
//   1) feats chunks PLAIN-indexed at 112B/px: odd stride spreads bank-quads
//      ((7L+c)%8) by itself; R10's rotate-7 canceled it (-> 8-way conflicts).
//      Also removes all mod-7 VALU on the frag path.
//   2) incremental chunk flush: ds_write_b128 each chunk as its 4 dwords
//      complete (c = 2,5,8,10,13,15) -> pk live range ~6 regs, kills residual
//      spills (R10: WRITE 84MB vs 64 ideal).
//   3) s_setprio(1) around MFMA clusters (2 waves/SIMD drift in the MLP phase);
//      hipFuncSetAttribute hoisted behind a static flag.

using bf16x8 = __attribute__((ext_vector_type(8))) __bf16;
using f32x4  = __attribute__((ext_vector_type(4))) float;

__device__ __forceinline__ unsigned f2bf(float f) {
    unsigned u = __float_as_uint(f);
    u += 0x7fffu + ((u >> 16) & 1u);   // RNE; inputs finite
    return u >> 16;
}

// ---- ws layout (ushort offsets): weight frags only ----
#define WS1_OFF 0        // [mt=8][kb=2][lane=64][8]  A-frags of W1^T (k=48 = b1)
#define WS2_OFF 8192     // [mt=8][kb=4][lane=64][8]  A-frags of W2^T
#define WS3_OFF 24576    // [kb=4][lane=64][8]        A-frags of W3^T

__global__ __launch_bounds__(256)
void prep_weights(const float* __restrict__ w1, const float* __restrict__ b1,
                  const float* __restrict__ w2, const float* __restrict__ w3,
                  unsigned short* __restrict__ ws) {
    const int gid = blockIdx.x * 256 + threadIdx.x;   // 13 blocks x 256 = 3328 slots
    if (gid < 1024) {   // ws1 (feature order k = 3*c + t; w1 row = t*16 + c; k=48 -> b1)
        const int s = gid;
        const int mt = s >> 7, kb = (s >> 6) & 1, lane = s & 63;
        const int q = lane >> 4, ln = lane & 15;
#pragma unroll
        for (int j = 0; j < 8; ++j) {
            const int k = kb * 32 + q * 8 + j;
            float val = 0.f;
            if (k < 48) { const int c = k / 3, t = k - 3 * c; val = w1[(t * 16 + c) * 128 + mt * 16 + ln]; }
            else if (k == 48) val = b1[mt * 16 + ln];   // bias column (B side supplies 1.0)
            ws[WS1_OFF + s * 8 + j] = (unsigned short)f2bf(val);
        }
    } else if (gid < 3072) {   // ws2
        const int s2 = gid - 1024;
        const int mt = s2 >> 8, kb = (s2 >> 6) & 3, lane = s2 & 63;
        const int q = lane >> 4, ln = lane & 15;
#pragma unroll
        for (int j = 0; j < 8; ++j) {
            const int k = kb * 32 + q * 8 + j;
            ws[WS2_OFF + s2 * 8 + j] = (unsigned short)f2bf(w2[k * 128 + mt * 16 + ln]);
        }
    } else if (gid < 3328) {   // ws3
        const int s3 = gid - 3072;
        const int kb = s3 >> 6, lane = s3 & 63;
        const int q = lane >> 4, ln = lane & 15;
#pragma unroll
        for (int j = 0; j < 8; ++j) {
            const int k = kb * 32 + q * 8 + j;
            ws[WS3_OFF + s3 * 8 + j] = (unsigned short)f2bf(w3[k * 16 + ln]);
        }
    }
}

// ===================== fused kernel =====================
// 512 blocks = 16 batches x 32 strips of 8 rows; 512 threads = 8 waves.
// Iteration i: waves 0-3 -> row r0, waves 4-7 -> row r0+1 (64 px per wave).

// LDS layout (bytes), total 160320 <= 163840 (1 block/CU, 8 waves = 2/SIMD):
#define SM_XS    0        // float xs[4][16][256] rolling row window  = 65536
#define SM_W2    65536    // W2 A-frags (also W1 bounce at init)      = 32768
#define SM_WR    98304    // 8 wave regions x 7168 (64px x 112B)      = 57344
#define SM_AUX   155648   // W3 A-frags                               = 4096
#define SM_B2L   159744   // b2[128] f32                              = 512
#define SM_B3L   160256   // b3[16] f32                               = 64
#define SM_TOTAL 160320

#define GLDS16(gp, lp) __builtin_amdgcn_global_load_lds(                     \
    (const __attribute__((address_space(1))) void*)(gp),                     \
    (__attribute__((address_space(3))) void*)(lp), 16, 0, 0)

// stage one (ch,row) pair -> xs[row&3][ch][*]; row/ch wave-uniform.
#define STAGE_UNIT(chv, rowv) do {                                           \
        const int _sl = (rowv) & 3;                                          \
        char* _ld = smem + SM_XS + (size_t)(((_sl) * 16 + (chv)) * 256) * 4; \
        if ((unsigned)(rowv) < 256u) {                                       \
            const float* _gs = xb + ((size_t)(chv) << 16)                    \
                             + (size_t)(unsigned)(rowv) * 256 + lane * 4;    \
            GLDS16(_gs, _ld);                                                \
        } else {                                                             \
            *(float4*)(_ld + lane * 16) = make_float4(0.f, 0.f, 0.f, 0.f);   \
        } } while (0)

// H chunk swizzle: j in 0..7, row = ln (16 rows x 128B)
#define HCH(j) ((((j) ^ (ln & 7)) << 4))

extern "C" __global__ __launch_bounds__(512)
void fused_kernel(const float* __restrict__ x, const float* __restrict__ fmask,
                  const unsigned short* __restrict__ wf,
                  const float* __restrict__ b2, const float* __restrict__ b3,
                  float* __restrict__ out) {
    extern __shared__ char smem[];
    float (*xs)[16][256] = (float (*)[16][256])(smem + SM_XS);
    char* W2L = smem + SM_W2;

    const int t = threadIdx.x;
    const int wv = t >> 6, lane = t & 63;
    const int q = lane >> 4, ln = lane & 15;
    const int rhalf = t >> 8;              // 0: waves 0-3, 1: waves 4-7
    const int col = t & 255;
    char* region = smem + SM_WR + wv * 7168;   // this wave's 64px feats/H/bounce

    const int bb = blockIdx.x >> 5;
    const int h0 = (blockIdx.x & 31) << 3;
    const float* xb = x + ((size_t)bb << 20);

    // ---- init staging: W1 via W2L bounce; W3/b2/b3 -> AUX ----
    {
        const uint4* s1 = (const uint4*)(wf + WS1_OFF);   // 16 KB
        uint4* dW = (uint4*)W2L;
        dW[t]       = s1[t];
        dW[t + 512] = s1[t + 512];
        if (t < 256) ((uint4*)(smem + SM_AUX))[t] = ((const uint4*)(wf + WS3_OFF))[t];
        if (t < 128) ((float*)(smem + SM_B2L))[t] = b2[t];
        if (t < 16)  ((float*)(smem + SM_B3L))[t] = b3[t];
    }
    __syncthreads();
    bf16x8 W1f[8][2];
#pragma unroll
    for (int mt = 0; mt < 8; ++mt) {
        W1f[mt][0] = *(const bf16x8*)(W2L + ((mt * 2 + 0) * 64 + lane) * 16);
        W1f[mt][1] = *(const bf16x8*)(W2L + ((mt * 2 + 1) * 64 + lane) * 16);
    }
    __syncthreads();
    {   // stage W2 frags (overwrites bounce area)
        const uint4* s2 = (const uint4*)(wf + WS2_OFF);   // 32 KB
        uint4* dW = (uint4*)W2L;
#pragma unroll
        for (int i2 = 0; i2 < 4; ++i2) dW[t + i2 * 512] = s2[t + i2 * 512];
    }

    // ---- Sobel column constants ----
    const int cL = (col > 0)   ? col - 1 : 0;
    const int cR = (col < 255) ? col + 1 : 255;
    const float mL = (col > 0)   ? 1.f : 0.f;
    const float mR = (col < 255) ? 1.f : 0.f;

    // ---- prologue: stage rows h0-1..h0+2 (64 units, 8 per wave) ----
#pragma unroll
    for (int k = 0; k < 8; ++k) {
        const int u = wv + 8 * k;
        STAGE_UNIT(u >> 2, h0 - 1 + (u & 3));
    }

    for (int i = 0; i < 4; ++i) {
        const int r0 = h0 + 2 * i;
        const int r  = r0 + rhalf;
        __syncthreads();   // staged rows complete; W2L ready (iter 0)
        const float fv = fmask[((size_t)bb << 16) + (size_t)r * 256 + col];

        // ---- Sobel + pack (thread = (rhalf, col)); chunks flushed as completed ----
        const int sT = (r - 1) & 3, sC = r & 3, sB = (r + 1) & 3;
        char* fb = region + lane * 112;   // this thread's pixel record (7 x 16B)
        unsigned pk[24];
        unsigned carry = 0;
#pragma unroll
        for (int c = 0; c < 16; ++c) {
            const float* rT = xs[sT][c];
            const float* rC = xs[sC][c];
            const float* rB = xs[sB][c];
            const float v00 = rT[cL] * mL, v01 = rT[col], v02 = rT[cR] * mR;
            const float v10 = rC[cL] * mL, v11 = rC[col], v12 = rC[cR] * mR;
            const float v20 = rB[cL] * mL, v21 = rB[col], v22 = rB[cR] * mR;
            const float sx = (v02 + 2.f * v12 + v22) - (v00 + 2.f * v10 + v20);
            const float sy = (v20 + 2.f * v21 + v22) - (v00 + 2.f * v01 + v02);
            if (c == 3) {   // exact fp32 3x3 maxpool of alpha (x >= 0 -> zero-pad safe)
                float mx = fmaxf(fmaxf(fmaxf(v00, v01), fmaxf(v02, v10)),
                                 fmaxf(fmaxf(v11, v12), fmaxf(fmaxf(v20, v21), v22)));
                const float selv = (mx > 0.1f) ? 1.f : 0.f;
                *(float*)(fb + 96) = (fv != 0.f) ? selv : 0.f;   // sel -> chunk 6
            }
            const unsigned ux = f2bf(v11), usx = f2bf(sx), usy = f2bf(sy);
            if ((c & 1) == 0) { pk[(c >> 1) * 3] = ux | (usx << 16); carry = usy; }
            else { pk[(c >> 1) * 3 + 1] = carry | (ux << 16);
                   pk[(c >> 1) * 3 + 2] = usx | (usy << 16); }
            // flush completed 16B chunks early (frees pk registers)
            if (c == 2)  *(uint4*)(fb +  0) = make_uint4(pk[0],  pk[1],  pk[2],  pk[3]);
            if (c == 5)  *(uint4*)(fb + 16) = make_uint4(pk[4],  pk[5],  pk[6],  pk[7]);
            if (c == 8)  *(uint4*)(fb + 32) = make_uint4(pk[8],  pk[9],  pk[10], pk[11]);
            if (c == 10) *(uint4*)(fb + 48) = make_uint4(pk[12], pk[13], pk[14], pk[15]);
            if (c == 13) *(uint4*)(fb + 64) = make_uint4(pk[16], pk[17], pk[18], pk[19]);
            if (c == 15) *(uint4*)(fb + 80) = make_uint4(pk[20], pk[21], pk[22], pk[23]);
        }
        __syncthreads();   // all waves done reading xs -> safe to restage
        if (i < 3) {       // rows r0+3, r0+4 fly under the MLP phase
#pragma unroll
            for (int k = 0; k < 4; ++k) {
                const int u = wv + 8 * k;
                STAGE_UNIT(u >> 1, r0 + 3 + (u & 1));
            }
        }

        // ---- MLP: 2 pairs; H(2KB two-phase) + bounce overlay the pair's slots ----
#pragma unroll
        for (int p = 0; p < 2; ++p) {
            char* Hb = region + p * 3584;
            // preload this pair's B-frags + sel (frees slots 2p, 2p+1)
            bf16x8 Bk0a[2], Bk1a[2];
            float sva[2];
#pragma unroll
            for (int s2 = 0; s2 < 2; ++s2) {
                const int s = p * 2 + s2;
                const char* fp = region + (s * 16 + ln) * 112;
                Bk0a[s2] = *(const bf16x8*)(fp + q * 16);
                bf16x8 t1 = {};
                if (q < 2)       t1 = *(const bf16x8*)(fp + (4 + q) * 16);
                else if (q == 2) t1[0] = (__bf16)1.0f;   // ones column k=48 (bias)
                Bk1a[s2] = t1;
                sva[s2] = *(const float*)(fp + 96);
            }
            f32x4 a3h;
#pragma unroll
            for (int s2 = 0; s2 < 2; ++s2) {
                // ---- layer 1, phase A (mt 0-3) ----
                bf16x8 B2[4];
                __builtin_amdgcn_s_setprio(1);
#pragma unroll
                for (int m = 0; m < 4; ++m) {
                    f32x4 a = {};
                    a = __builtin_amdgcn_mfma_f32_16x16x32_bf16(W1f[m][0], Bk0a[s2], a, 0, 0, 0);
                    a = __builtin_amdgcn_mfma_f32_16x16x32_bf16(W1f[m][1], Bk1a[s2], a, 0, 0, 0);
                    const unsigned r01 = f2bf(fmaxf(a[0], 0.f)) | (f2bf(fmaxf(a[1], 0.f)) << 16);
                    const unsigned r23 = f2bf(fmaxf(a[2], 0.f)) | (f2bf(fmaxf(a[3], 0.f)) << 16);
                    *(uint2*)(Hb + ln * 128 + HCH(m * 2 + (q >> 1)) + ((q & 1) << 3))
                        = make_uint2(r01, r23);
                }
                __builtin_amdgcn_s_setprio(0);
                B2[0] = *(const bf16x8*)(Hb + ln * 128 + HCH(q));
                B2[1] = *(const bf16x8*)(Hb + ln * 128 + HCH(4 + q));
                // ---- layer 1, phase B (mt 4-7, same 2KB) ----
                __builtin_amdgcn_s_setprio(1);
#pragma unroll
                for (int m = 4; m < 8; ++m) {
                    f32x4 a = {};
                    a = __builtin_amdgcn_mfma_f32_16x16x32_bf16(W1f[m][0], Bk0a[s2], a, 0, 0, 0);
                    a = __builtin_amdgcn_mfma_f32_16x16x32_bf16(W1f[m][1], Bk1a[s2], a, 0, 0, 0);
                    const unsigned r01 = f2bf(fmaxf(a[0], 0.f)) | (f2bf(fmaxf(a[1], 0.f)) << 16);
                    const unsigned r23 = f2bf(fmaxf(a[2], 0.f)) | (f2bf(fmaxf(a[3], 0.f)) << 16);
                    *(uint2*)(Hb + ln * 128 + HCH((m - 4) * 2 + (q >> 1)) + ((q & 1) << 3))
                        = make_uint2(r01, r23);
                }
                __builtin_amdgcn_s_setprio(0);
                B2[2] = *(const bf16x8*)(Hb + ln * 128 + HCH(q));
                B2[3] = *(const bf16x8*)(Hb + ln * 128 + HCH(4 + q));
                // ---- layer 2, phase A (mt 0-3; bias from LDS) ----
                bf16x8 B3[4];
                __builtin_amdgcn_s_setprio(1);
#pragma unroll
                for (int m = 0; m < 4; ++m) {
                    f32x4 a = *(const f32x4*)(smem + SM_B2L + m * 64 + q * 16);
#pragma unroll
                    for (int kb = 0; kb < 4; ++kb) {
                        const bf16x8 Af = *(const bf16x8*)(W2L + ((m * 4 + kb) * 64 + lane) * 16);
                        a = __builtin_amdgcn_mfma_f32_16x16x32_bf16(Af, B2[kb], a, 0, 0, 0);
                    }
                    const unsigned r01 = f2bf(fmaxf(a[0], 0.f)) | (f2bf(fmaxf(a[1], 0.f)) << 16);
                    const unsigned r23 = f2bf(fmaxf(a[2], 0.f)) | (f2bf(fmaxf(a[3], 0.f)) << 16);
                    *(uint2*)(Hb + ln * 128 + HCH(m * 2 + (q >> 1)) + ((q & 1) << 3))
                        = make_uint2(r01, r23);
                }
                __builtin_amdgcn_s_setprio(0);
                B3[0] = *(const bf16x8*)(Hb + ln * 128 + HCH(q));
                B3[1] = *(const bf16x8*)(Hb + ln * 128 + HCH(4 + q));
                // ---- layer 2, phase B (mt 4-7) ----
                __builtin_amdgcn_s_setprio(1);
#pragma unroll
                for (int m = 4; m < 8; ++m) {
                    f32x4 a = *(const f32x4*)(smem + SM_B2L + m * 64 + q * 16);
#pragma unroll
                    for (int kb = 0; kb < 4; ++kb) {
                        const bf16x8 Af = *(const bf16x8*)(W2L + ((m * 4 + kb) * 64 + lane) * 16);
                        a = __builtin_amdgcn_mfma_f32_16x16x32_bf16(Af, B2[kb], a, 0, 0, 0);
                    }
                    const unsigned r01 = f2bf(fmaxf(a[0], 0.f)) | (f2bf(fmaxf(a[1], 0.f)) << 16);
                    const unsigned r23 = f2bf(fmaxf(a[2], 0.f)) | (f2bf(fmaxf(a[3], 0.f)) << 16);
                    *(uint2*)(Hb + ln * 128 + HCH((m - 4) * 2 + (q >> 1)) + ((q & 1) << 3))
                        = make_uint2(r01, r23);
                }
                __builtin_amdgcn_s_setprio(0);
                B3[2] = *(const bf16x8*)(Hb + ln * 128 + HCH(q));
                B3[3] = *(const bf16x8*)(Hb + ln * 128 + HCH(4 + q));
                // ---- layer 3 (W3 frags + bias from LDS) ----
                f32x4 a3 = *(const f32x4*)(smem + SM_B3L + q * 16);
                __builtin_amdgcn_s_setprio(1);
#pragma unroll
                for (int kb = 0; kb < 4; ++kb) {
                    const bf16x8 W3a = *(const bf16x8*)(smem + SM_AUX + (kb * 64 + lane) * 16);
                    a3 = __builtin_amdgcn_mfma_f32_16x16x32_bf16(W3a, B3[kb], a3, 0, 0, 0);
                }
                __builtin_amdgcn_s_setprio(0);
                const float svv = sva[s2];
#pragma unroll
                for (int r4 = 0; r4 < 4; ++r4) a3[r4] *= svv;
                if (s2 == 0) a3h = a3;
                else {   // H dead -> write pair bounce [ch][2x16px], 132B rows
#pragma unroll
                    for (int r4 = 0; r4 < 4; ++r4) {
                        *(float*)(Hb + (q * 4 + r4) * 132 + ln * 4)      = a3h[r4];
                        *(float*)(Hb + (q * 4 + r4) * 132 + 64 + ln * 4) = a3[r4];
                    }
                }
            }
        }
        // ---- stores: per channel, 64 lanes x 4B = full aligned 256 B line ----
        {
            float* orow = out + (((size_t)(bb * 16)) << 16) + (size_t)r * 256
                        + (wv & 3) * 64 + lane;
#pragma unroll
            for (int ch = 0; ch < 16; ++ch) {
                const float v = *(const float*)(region + (lane >> 5) * 3584
                              + ch * 132 + ((lane >> 4) & 1) * 64 + (lane & 15) * 4);
                orow[(size_t)ch << 16] = v;
            }
        }
    }
}

extern "C" void kernel_launch(void* const* d_in, const int* in_sizes, int n_in,
                              void* d_out, int out_size, void* d_ws, size_t ws_size,
                              hipStream_t stream) {
    (void)in_sizes; (void)n_in; (void)out_size; (void)ws_size;
    const float* x  = (const float*)d_in[0];
    const float* fm = (const float*)d_in[1];
    const float* w1 = (const float*)d_in[2];
    const float* b1 = (const float*)d_in[3];
    const float* w2 = (const float*)d_in[4];
    const float* b2 = (const float*)d_in[5];
    const float* w3 = (const float*)d_in[6];
    const float* b3 = (const float*)d_in[7];
    float* o = (float*)d_out;
    unsigned short* ws = (unsigned short*)d_ws;

    prep_weights<<<dim3(13), dim3(256), 0, stream>>>(w1, b1, w2, w3, ws);

    static bool s_attr_done = false;
    if (!s_attr_done) {
        hipFuncSetAttribute((const void*)fused_kernel,
                            hipFuncAttributeMaxDynamicSharedMemorySize, SM_TOTAL);
        s_attr_done = true;
    }
    fused_kernel<<<dim3(512), dim3(512), SM_TOTAL, stream>>>(x, fm, ws, b2, b3, o);
}

// Round 9
// 210.904 us; speedup vs baseline: 1.4966x; 1.0473x over previous
//
#include <hip/hip_runtime.h>

// Round 12: VALU pass.
//   1) bf16 conversion via native (__bf16) casts -> compiler emits
//      v_cvt_pk_bf16_f32 (1 instr / 2 vals) instead of 5-instr bit-RNE.
//      ~64 conversions/sub in MLP + 48 in Sobel were ~40% of VALU work.
//      Sobel restructured into 2-channel groups for clean (lo,hi) pack pairs.
//   2) all-4 sub B-frag preload (+18 regs, ~118 total) frees the whole wave
//      region -> single-phase H (4KB, R8-verified layout): half the LDS
//      write->read turnarounds vs R10/R11 two-phase. Per-pair bounce (132B
//      rows) + R5-verified 128B-line stores.
// Canary: WRITE_SIZE must stay 65536 KB (spill-free).

using bf16x8 = __attribute__((ext_vector_type(8))) __bf16;
using f32x4  = __attribute__((ext_vector_type(4))) float;

__device__ __forceinline__ unsigned f2bf(float f) {
    unsigned u = __float_as_uint(f);
    u += 0x7fffu + ((u >> 16) & 1u);   // RNE; inputs finite (prep only)
    return u >> 16;
}

__device__ __forceinline__ unsigned pack2bf(float lo, float hi) {
    // native casts -> v_cvt_pk_bf16_f32 (RNE, identical to f2bf)
    unsigned short a = __builtin_bit_cast(unsigned short, (__bf16)lo);
    unsigned short b = __builtin_bit_cast(unsigned short, (__bf16)hi);
    return (unsigned)a | ((unsigned)b << 16);
}

// ---- ws layout (ushort offsets): weight frags only ----
#define WS1_OFF 0        // [mt=8][kb=2][lane=64][8]  A-frags of W1^T (k=48 = b1)
#define WS2_OFF 8192     // [mt=8][kb=4][lane=64][8]  A-frags of W2^T
#define WS3_OFF 24576    // [kb=4][lane=64][8]        A-frags of W3^T

__global__ __launch_bounds__(256)
void prep_weights(const float* __restrict__ w1, const float* __restrict__ b1,
                  const float* __restrict__ w2, const float* __restrict__ w3,
                  unsigned short* __restrict__ ws) {
    const int gid = blockIdx.x * 256 + threadIdx.x;   // 13 blocks x 256 = 3328 slots
    if (gid < 1024) {   // ws1 (feature order k = 3*c + t; w1 row = t*16 + c; k=48 -> b1)
        const int s = gid;
        const int mt = s >> 7, kb = (s >> 6) & 1, lane = s & 63;
        const int q = lane >> 4, ln = lane & 15;
#pragma unroll
        for (int j = 0; j < 8; ++j) {
            const int k = kb * 32 + q * 8 + j;
            float val = 0.f;
            if (k < 48) { const int c = k / 3, t = k - 3 * c; val = w1[(t * 16 + c) * 128 + mt * 16 + ln]; }
            else if (k == 48) val = b1[mt * 16 + ln];   // bias column (B side supplies 1.0)
            ws[WS1_OFF + s * 8 + j] = (unsigned short)f2bf(val);
        }
    } else if (gid < 3072) {   // ws2
        const int s2 = gid - 1024;
        const int mt = s2 >> 8, kb = (s2 >> 6) & 3, lane = s2 & 63;
        const int q = lane >> 4, ln = lane & 15;
#pragma unroll
        for (int j = 0; j < 8; ++j) {
            const int k = kb * 32 + q * 8 + j;
            ws[WS2_OFF + s2 * 8 + j] = (unsigned short)f2bf(w2[k * 128 + mt * 16 + ln]);
        }
    } else if (gid < 3328) {   // ws3
        const int s3 = gid - 3072;
        const int kb = s3 >> 6, lane = s3 & 63;
        const int q = lane >> 4, ln = lane & 15;
#pragma unroll
        for (int j = 0; j < 8; ++j) {
            const int k = kb * 32 + q * 8 + j;
            ws[WS3_OFF + s3 * 8 + j] = (unsigned short)f2bf(w3[k * 16 + ln]);
        }
    }
}

// ===================== fused kernel =====================
// 512 blocks = 16 batches x 32 strips of 8 rows; 512 threads = 8 waves.
// Iteration i: waves 0-3 -> row r0, waves 4-7 -> row r0+1 (64 px per wave).

// LDS layout (bytes), total 160320 <= 163840 (1 block/CU, 8 waves = 2/SIMD):
#define SM_XS    0        // float xs[4][16][256] rolling row window  = 65536
#define SM_W2    65536    // W2 A-frags (also W1 bounce at init)      = 32768
#define SM_WR    98304    // 8 wave regions x 7168 (64px x 112B)      = 57344
#define SM_AUX   155648   // W3 A-frags                               = 4096
#define SM_B2L   159744   // b2[128] f32                              = 512
#define SM_B3L   160256   // b3[16] f32                               = 64
#define SM_TOTAL 160320

#define GLDS16(gp, lp) __builtin_amdgcn_global_load_lds(                     \
    (const __attribute__((address_space(1))) void*)(gp),                     \
    (__attribute__((address_space(3))) void*)(lp), 16, 0, 0)

// stage one (ch,row) pair -> xs[row&3][ch][*]; row/ch wave-uniform.
#define STAGE_UNIT(chv, rowv) do {                                           \
        const int _sl = (rowv) & 3;                                          \
        char* _ld = smem + SM_XS + (size_t)(((_sl) * 16 + (chv)) * 256) * 4; \
        if ((unsigned)(rowv) < 256u) {                                       \
            const float* _gs = xb + ((size_t)(chv) << 16)                    \
                             + (size_t)(unsigned)(rowv) * 256 + lane * 4;    \
            GLDS16(_gs, _ld);                                                \
        } else {                                                             \
            *(float4*)(_ld + lane * 16) = make_float4(0.f, 0.f, 0.f, 0.f);   \
        } } while (0)

// H chunk swizzle (single-phase, R8 layout): j in 0..15, 16 rows x 256B
#define HCH(j) ((((j) ^ (ln & 7)) << 4))

extern "C" __global__ __launch_bounds__(512)
void fused_kernel(const float* __restrict__ x, const float* __restrict__ fmask,
                  const unsigned short* __restrict__ wf,
                  const float* __restrict__ b2, const float* __restrict__ b3,
                  float* __restrict__ out) {
    extern __shared__ char smem[];
    float (*xs)[16][256] = (float (*)[16][256])(smem + SM_XS);
    char* W2L = smem + SM_W2;

    const int t = threadIdx.x;
    const int wv = t >> 6, lane = t & 63;
    const int q = lane >> 4, ln = lane & 15;
    const int rhalf = t >> 8;              // 0: waves 0-3, 1: waves 4-7
    const int col = t & 255;
    char* region = smem + SM_WR + wv * 7168;   // feats -> H(4KB) + bounce(2.1KB)
    char* H = region;
    float* bounce = (float*)(region + 4096);   // [16 ch][32 px] rows of 132B

    const int bb = blockIdx.x >> 5;
    const int h0 = (blockIdx.x & 31) << 3;
    const float* xb = x + ((size_t)bb << 20);

    // ---- init staging: W1 via W2L bounce; W3/b2/b3 -> AUX ----
    {
        const uint4* s1 = (const uint4*)(wf + WS1_OFF);   // 16 KB
        uint4* dW = (uint4*)W2L;
        dW[t]       = s1[t];
        dW[t + 512] = s1[t + 512];
        if (t < 256) ((uint4*)(smem + SM_AUX))[t] = ((const uint4*)(wf + WS3_OFF))[t];
        if (t < 128) ((float*)(smem + SM_B2L))[t] = b2[t];
        if (t < 16)  ((float*)(smem + SM_B3L))[t] = b3[t];
    }
    __syncthreads();
    bf16x8 W1f[8][2];
#pragma unroll
    for (int mt = 0; mt < 8; ++mt) {
        W1f[mt][0] = *(const bf16x8*)(W2L + ((mt * 2 + 0) * 64 + lane) * 16);
        W1f[mt][1] = *(const bf16x8*)(W2L + ((mt * 2 + 1) * 64 + lane) * 16);
    }
    __syncthreads();
    {   // stage W2 frags (overwrites bounce area)
        const uint4* s2 = (const uint4*)(wf + WS2_OFF);   // 32 KB
        uint4* dW = (uint4*)W2L;
#pragma unroll
        for (int i2 = 0; i2 < 4; ++i2) dW[t + i2 * 512] = s2[t + i2 * 512];
    }

    // ---- Sobel column constants ----
    const int cL = (col > 0)   ? col - 1 : 0;
    const int cR = (col < 255) ? col + 1 : 255;
    const float mL = (col > 0)   ? 1.f : 0.f;
    const float mR = (col < 255) ? 1.f : 0.f;

    // ---- prologue: stage rows h0-1..h0+2 (64 units, 8 per wave) ----
#pragma unroll
    for (int k = 0; k < 8; ++k) {
        const int u = wv + 8 * k;
        STAGE_UNIT(u >> 2, h0 - 1 + (u & 3));
    }

    for (int i = 0; i < 4; ++i) {
        const int r0 = h0 + 2 * i;
        const int r  = r0 + rhalf;
        __syncthreads();   // staged rows complete; W2L ready (iter 0)
        const float fv = fmask[((size_t)bb << 16) + (size_t)r * 256 + col];

        // ---- Sobel: 2-channel groups, cvt_pk packing, early chunk flush ----
        const int sT = (r - 1) & 3, sC = r & 3, sB = (r + 1) & 3;
        char* fb = region + lane * 112;   // this thread's pixel record (7 x 16B)
        unsigned pk[24];
#pragma unroll
        for (int g = 0; g < 8; ++g) {
            float va[2], sxa[2], sya[2];
#pragma unroll
            for (int h = 0; h < 2; ++h) {
                const int c = 2 * g + h;
                const float* rT = xs[sT][c];
                const float* rC = xs[sC][c];
                const float* rB = xs[sB][c];
                const float v00 = rT[cL] * mL, v01 = rT[col], v02 = rT[cR] * mR;
                const float v10 = rC[cL] * mL, v11 = rC[col], v12 = rC[cR] * mR;
                const float v20 = rB[cL] * mL, v21 = rB[col], v22 = rB[cR] * mR;
                sxa[h] = (v02 + 2.f * v12 + v22) - (v00 + 2.f * v10 + v20);
                sya[h] = (v20 + 2.f * v21 + v22) - (v00 + 2.f * v01 + v02);
                va[h] = v11;
                if (g == 1 && h == 1) {   // c==3: exact fp32 3x3 maxpool of alpha
                    float mx = fmaxf(fmaxf(fmaxf(v00, v01), fmaxf(v02, v10)),
                                     fmaxf(fmaxf(v11, v12), fmaxf(fmaxf(v20, v21), v22)));
                    const float selv = (mx > 0.1f) ? 1.f : 0.f;
                    *(float*)(fb + 96) = (fv != 0.f) ? selv : 0.f;   // sel -> chunk 6
                }
            }
            pk[g * 3 + 0] = pack2bf(va[0],  sxa[0]);
            pk[g * 3 + 1] = pack2bf(sya[0], va[1]);
            pk[g * 3 + 2] = pack2bf(sxa[1], sya[1]);
            if (g == 1) *(uint4*)(fb +  0) = make_uint4(pk[0],  pk[1],  pk[2],  pk[3]);
            if (g == 3) { *(uint4*)(fb + 16) = make_uint4(pk[4],  pk[5],  pk[6],  pk[7]);
                          *(uint4*)(fb + 32) = make_uint4(pk[8],  pk[9],  pk[10], pk[11]); }
            if (g == 5) *(uint4*)(fb + 48) = make_uint4(pk[12], pk[13], pk[14], pk[15]);
            if (g == 6) *(uint4*)(fb + 64) = make_uint4(pk[16], pk[17], pk[18], pk[19]);
            if (g == 7) *(uint4*)(fb + 80) = make_uint4(pk[20], pk[21], pk[22], pk[23]);
        }
        __syncthreads();   // all waves done reading xs -> safe to restage
        if (i < 3) {       // rows r0+3, r0+4 fly under the MLP phase
#pragma unroll
            for (int k = 0; k < 4; ++k) {
                const int u = wv + 8 * k;
                STAGE_UNIT(u >> 1, r0 + 3 + (u & 1));
            }
        }

        // ---- preload ALL 4 subs' B-frags + sel (whole region freed for H) ----
        bf16x8 Bk0[4], Bk1[4];
        float sv[4];
#pragma unroll
        for (int s = 0; s < 4; ++s) {
            const char* fp = region + (s * 16 + ln) * 112;
            Bk0[s] = *(const bf16x8*)(fp + q * 16);
            bf16x8 t1 = {};
            if (q < 2)       t1 = *(const bf16x8*)(fp + (4 + q) * 16);
            else if (q == 2) t1[0] = (__bf16)1.0f;   // ones column k=48 (bias)
            Bk1[s] = t1;
            sv[s] = *(const float*)(fp + 96);
        }

        // ---- MLP: 2 pairs; single-phase H (4KB); per-pair bounce + stores ----
#pragma unroll
        for (int p = 0; p < 2; ++p) {
            f32x4 a3h;
#pragma unroll
            for (int s2 = 0; s2 < 2; ++s2) {
                const int s = 2 * p + s2;
                // layer 1 (bias via k=48 column)
                __builtin_amdgcn_s_setprio(1);
#pragma unroll
                for (int mt = 0; mt < 8; ++mt) {
                    f32x4 a = {};
                    a = __builtin_amdgcn_mfma_f32_16x16x32_bf16(W1f[mt][0], Bk0[s], a, 0, 0, 0);
                    a = __builtin_amdgcn_mfma_f32_16x16x32_bf16(W1f[mt][1], Bk1[s], a, 0, 0, 0);
                    const unsigned r01 = pack2bf(fmaxf(a[0], 0.f), fmaxf(a[1], 0.f));
                    const unsigned r23 = pack2bf(fmaxf(a[2], 0.f), fmaxf(a[3], 0.f));
                    *(uint2*)(H + ln * 256 + HCH(mt * 2 + (q >> 1)) + ((q & 1) << 3))
                        = make_uint2(r01, r23);
                }
                __builtin_amdgcn_s_setprio(0);
                bf16x8 B2[4];
#pragma unroll
                for (int kb = 0; kb < 4; ++kb)
                    B2[kb] = *(const bf16x8*)(H + ln * 256 + HCH(kb * 4 + q));
                // layer 2 (W2 A-frags + bias from LDS)
                __builtin_amdgcn_s_setprio(1);
#pragma unroll
                for (int mt = 0; mt < 8; ++mt) {
                    f32x4 a = *(const f32x4*)(smem + SM_B2L + mt * 64 + q * 16);
#pragma unroll
                    for (int kb = 0; kb < 4; ++kb) {
                        const bf16x8 Af = *(const bf16x8*)(W2L + ((mt * 4 + kb) * 64 + lane) * 16);
                        a = __builtin_amdgcn_mfma_f32_16x16x32_bf16(Af, B2[kb], a, 0, 0, 0);
                    }
                    const unsigned r01 = pack2bf(fmaxf(a[0], 0.f), fmaxf(a[1], 0.f));
                    const unsigned r23 = pack2bf(fmaxf(a[2], 0.f), fmaxf(a[3], 0.f));
                    *(uint2*)(H + ln * 256 + HCH(mt * 2 + (q >> 1)) + ((q & 1) << 3))
                        = make_uint2(r01, r23);
                }
                __builtin_amdgcn_s_setprio(0);
                bf16x8 B3[4];
#pragma unroll
                for (int kb = 0; kb < 4; ++kb)
                    B3[kb] = *(const bf16x8*)(H + ln * 256 + HCH(kb * 4 + q));
                // layer 3 (W3 frags + bias from LDS)
                f32x4 a3 = *(const f32x4*)(smem + SM_B3L + q * 16);
                __builtin_amdgcn_s_setprio(1);
#pragma unroll
                for (int kb = 0; kb < 4; ++kb) {
                    const bf16x8 W3a = *(const bf16x8*)(smem + SM_AUX + (kb * 64 + lane) * 16);
                    a3 = __builtin_amdgcn_mfma_f32_16x16x32_bf16(W3a, B3[kb], a3, 0, 0, 0);
                }
                __builtin_amdgcn_s_setprio(0);
                const float svv = sv[s];
#pragma unroll
                for (int r4 = 0; r4 < 4; ++r4) a3[r4] *= svv;
                if (s2 == 0) a3h = a3;
                else {   // write pair bounce [ch][2x16px], rows of 33 floats
#pragma unroll
                    for (int r4 = 0; r4 < 4; ++r4) {
                        bounce[(q * 4 + r4) * 33 + ln]      = a3h[r4];
                        bounce[(q * 4 + r4) * 33 + 16 + ln] = a3[r4];
                    }
                }
            }
            // ---- store pair: per 2 channels, 32 lanes x 4B = 128B lines ----
            {
                const int px32 = lane & 31;
                const int chb  = lane >> 5;
                float* orow = out + (((size_t)(bb * 16)) << 16) + (size_t)r * 256
                            + (wv & 3) * 64 + p * 32 + px32;
#pragma unroll
                for (int i8 = 0; i8 < 8; ++i8) {
                    const int ch = chb + 2 * i8;
                    orow[(size_t)ch << 16] = bounce[ch * 33 + px32];
                }
            }
        }
    }
}

extern "C" void kernel_launch(void* const* d_in, const int* in_sizes, int n_in,
                              void* d_out, int out_size, void* d_ws, size_t ws_size,
                              hipStream_t stream) {
    (void)in_sizes; (void)n_in; (void)out_size; (void)ws_size;
    const float* x  = (const float*)d_in[0];
    const float* fm = (const float*)d_in[1];
    const float* w1 = (const float*)d_in[2];
    const float* b1 = (const float*)d_in[3];
    const float* w2 = (const float*)d_in[4];
    const float* b2 = (const float*)d_in[5];
    const float* w3 = (const float*)d_in[6];
    const float* b3 = (const float*)d_in[7];
    float* o = (float*)d_out;
    unsigned short* ws = (unsigned short*)d_ws;

    prep_weights<<<dim3(13), dim3(256), 0, stream>>>(w1, b1, w2, w3, ws);

    static bool s_attr_done = false;
    if (!s_attr_done) {
        hipFuncSetAttribute((const void*)fused_kernel,
                            hipFuncAttributeMaxDynamicSharedMemorySize, SM_TOTAL);
        s_attr_done = true;
    }
    fused_kernel<<<dim3(512), dim3(512), SM_TOTAL, stream>>>(x, fm, ws, b2, b3, o);
}